// Round 5
// baseline (33.225 us; speedup 1.0000x reference)
//
#include <hip/hip_runtime.h>

constexpr int NB = 32;
constexpr int NPAIR = NB * NB;          // 1024
constexpr int HSIZE = NPAIR + NB;       // 1056 logical bins
constexpr int NCOPY = 16;               // interleaved copies: addr = bin*16 + (lane&15)
constexpr int LWORDS = HSIZE * NCOPY;   // 16896 words = 67.6 KB LDS
constexpr int DD = 96, HH = 96, WW = 96;
constexpr int SD = HH * WW;             // 9216
constexpr int SH = WW;                  // 96
constexpr int NVOX = 2 * DD * HH * WW;  // 1769472
constexpr int NCH = NVOX / 4;           // 442368 chunks of 4 voxels
constexpr int CW = WW / 4;              // 24 chunks per row
constexpr int NBLK = NCH / 256;         // 1728: exactly 1 chunk per thread
constexpr int NPART = 32;               // global partial histograms

__global__ void zero_kernel(unsigned int* ws, int n) {
    int t = blockIdx.x * blockDim.x + threadIdx.x;
    if (t < n) ws[t] = 0u;
}

__global__ __launch_bounds__(256) void adj_kernel(const int* __restrict__ tgt,
                                                  unsigned int* __restrict__ ws) {
    __shared__ unsigned int hist[LWORDS];
    uint4* h4 = (uint4*)hist;
    for (int k = threadIdx.x; k < LWORDS / 4; k += 256)
        h4[k] = make_uint4(0u, 0u, 0u, 0u);
    __syncthreads();

    const int c  = blockIdx.x * 256 + threadIdx.x;   // grid sized exactly
    const int cw = c % CW;
    const int r  = c / CW;
    const int h  = r % HH;
    const int d  = (r / HH) % DD;    // batch boundary handled by dp guard
    const int v0 = c * 4;
    const unsigned int cp = threadIdx.x & (NCOPY - 1);   // this lane's copy

    const bool hpv = (h + 1 < HH), hmv = (h > 0), dpv = (d + 1 < DD);
    const bool vL = (cw > 0), vR = (cw < CW - 1);

    int4 Cc = *(const int4*)(tgt + v0);
    int ci[4] = {Cc.x, Cc.y, Cc.z, Cc.w};
    int cR = vR ? tgt[v0 + 4] : 0;

    // neighbor rows for the 13 lexicographically-positive offsets:
    // (0,+1,*), (+1,-1,*), (+1,0,*), (+1,+1,*); plus (0,0,+1) in-row
    bool rowv[4];
    rowv[0] = hpv; rowv[1] = dpv && hmv; rowv[2] = dpv; rowv[3] = dpv && hpv;
    const int roff[4] = {SH, SD - SH, SD, SD + SH};
    int a[4][6];
#pragma unroll
    for (int q = 0; q < 4; q++) {
        if (rowv[q]) {
            const int* p = tgt + v0 + roff[q];
            int4 m = *(const int4*)p;
            a[q][1] = m.x; a[q][2] = m.y; a[q][3] = m.z; a[q][4] = m.w;
            a[q][0] = vL ? p[-1] : 0;
            a[q][5] = vR ? p[4]  : 0;
        }
    }

#pragma unroll
    for (int e = 0; e < 4; e++) {
        // pair bin (i,j) lives at ((i*32+j)<<4) + cp ; center bin at ((NPAIR+i)<<4)+cp
        unsigned int ibc = (((unsigned int)ci[e]) << 9) + cp;
        atomicAdd(&hist[((NPAIR + ci[e]) << 4) + cp], 1u);        // center (diag)
        if (e < 3)       atomicAdd(&hist[ibc + (ci[e + 1] << 4)], 1u);  // (0,0,+1)
        else if (vR)     atomicAdd(&hist[ibc + (cR << 4)], 1u);
#pragma unroll
        for (int q = 0; q < 4; q++) {
            if (rowv[q]) {
                if (e > 0 || vL) atomicAdd(&hist[ibc + (a[q][e] << 4)], 1u);
                atomicAdd(&hist[ibc + (a[q][e + 1] << 4)], 1u);
                if (e < 3 || vR) atomicAdd(&hist[ibc + (a[q][e + 2] << 4)], 1u);
            }
        }
    }
    __syncthreads();

    // flush: rotate copy index per-lane so reads stay ~2-way per bank (free)
    unsigned int* part = ws + (size_t)(blockIdx.x & (NPART - 1)) * HSIZE;
    for (int k = threadIdx.x; k < HSIZE; k += 256) {
        unsigned int s = 0;
#pragma unroll
        for (int cc = 0; cc < NCOPY; cc++)
            s += hist[(k << 4) + ((cc + threadIdx.x) & (NCOPY - 1))];
        if (s) atomicAdd(&part[k], s);
    }
}

// single block, 1024 threads: coalesced sum of 32 partials, then LDS symmetrize
__global__ __launch_bounds__(1024) void final_kernel(const unsigned int* __restrict__ ws,
                                                     float* __restrict__ out) {
    __shared__ unsigned int s[NPAIR];
    __shared__ unsigned int nn[NB];
    const int k = threadIdx.x;
    unsigned int acc = 0;
#pragma unroll 8
    for (int p = 0; p < NPART; ++p) acc += ws[p * HSIZE + k];
    s[k] = acc;
    if (k < NB) {
        unsigned int a2 = 0;
#pragma unroll 8
        for (int p = 0; p < NPART; ++p) a2 += ws[p * HSIZE + NPAIR + k];
        nn[k] = a2;
    }
    __syncthreads();
    const int i = k >> 5, j = k & 31;
    unsigned int v = s[k] + s[(j << 5) | i];
    if (i == j) v += nn[i];
    out[k] = (float)v;
}

extern "C" void kernel_launch(void* const* d_in, const int* in_sizes, int n_in,
                              void* d_out, int out_size, void* d_ws, size_t ws_size,
                              hipStream_t stream) {
    const int* tgt = (const int*)d_in[0];
    float* out = (float*)d_out;
    unsigned int* ws = (unsigned int*)d_ws;

    const int zn = NPART * HSIZE;   // 33792 words
    zero_kernel<<<(zn + 255) / 256, 256, 0, stream>>>(ws, zn);
    adj_kernel<<<NBLK, 256, 0, stream>>>(tgt, ws);
    final_kernel<<<1, 1024, 0, stream>>>(ws, out);
}

// Round 6
// 27.487 us; speedup vs baseline: 1.2088x; 1.2088x over previous
//
#include <hip/hip_runtime.h>

constexpr int NB = 32;
constexpr int NPAIR = NB * NB;          // 1024 pair bins
constexpr int HSIZE = NPAIR + NB;       // 1056 unpacked bins per global partial
constexpr int NW = 528;                 // packed pair words (2 bins/word)
constexpr int HW = NW + 16;             // + 16 packed diag words = 544
constexpr int NCPY = 8;                 // interleaved copies, c = lane&7
constexpr int LWORDS = HW * NCPY;       // 4352 words = 17.4 KB
constexpr int DD = 96, HH = 96, WW = 96;
constexpr int SD = HH * WW;             // 9216
constexpr int SH = WW;                  // 96
constexpr int NVOX = 2 * DD * HH * WW;  // 1769472
constexpr int NCH = NVOX / 4;           // 442368 chunks of 4 voxels
constexpr int CW = WW / 4;              // 24 chunks per row
constexpr int NBLK = NCH / 256;         // 1728: exactly 1 chunk per thread
constexpr int NPART = 32;               // global partial histograms

__global__ void zero_kernel(unsigned int* ws, int n) {
    int t = blockIdx.x * blockDim.x + threadIdx.x;
    if (t < n) ws[t] = 0u;
}

__global__ __launch_bounds__(256) void adj_kernel(const int* __restrict__ tgt,
                                                  unsigned int* __restrict__ ws) {
    __shared__ unsigned int hist[LWORDS];
    uint4* h4 = (uint4*)hist;
    for (int k = threadIdx.x; k < LWORDS / 4; k += 256)
        h4[k] = make_uint4(0u, 0u, 0u, 0u);
    __syncthreads();

    const int c  = blockIdx.x * 256 + threadIdx.x;   // grid sized exactly
    const int cw = c % CW;
    const int r  = c / CW;
    const int h  = r % HH;
    const int d  = (r / HH) % DD;    // batch boundary handled by dp guard
    const int v0 = c * 4;
    const unsigned int c8 = threadIdx.x & (NCPY - 1);

    const bool hpv = (h + 1 < HH), hmv = (h > 0), dpv = (d + 1 < DD);
    const bool vL = (cw > 0), vR = (cw < CW - 1);

    int4 Cc = *(const int4*)(tgt + v0);
    int ci[4] = {Cc.x, Cc.y, Cc.z, Cc.w};
    int cR = vR ? tgt[v0 + 4] : 0;

    // neighbor rows for the 13 lexicographically-positive offsets:
    // (0,+1,*), (+1,-1,*), (+1,0,*), (+1,+1,*); plus (0,0,+1) in-row
    bool rowv[4];
    rowv[0] = hpv; rowv[1] = dpv && hmv; rowv[2] = dpv; rowv[3] = dpv && hpv;
    const int roff[4] = {SH, SD - SH, SD, SD + SH};
    int a[4][6];
#pragma unroll
    for (int q = 0; q < 4; q++) {
        if (rowv[q]) {
            const int* p = tgt + v0 + roff[q];
            int4 m = *(const int4*)p;
            a[q][1] = m.x; a[q][2] = m.y; a[q][3] = m.z; a[q][4] = m.w;
            a[q][0] = vL ? p[-1] : 0;
            a[q][5] = vR ? p[4]  : 0;
        }
    }

#pragma unroll
    for (int e = 0; e < 4; e++) {
        const unsigned int base = ((unsigned int)ci[e]) << 4;   // i*16 packed words
        // center diag: packed word 512 + (i>>1), half by i&1
        atomicAdd(&hist[((unsigned)(NW + (ci[e] >> 1)) << 3) + c8],
                  1u << ((ci[e] & 1) << 4));
        auto upd = [&](int j) {
            unsigned int w = base + (unsigned)(j >> 1);
            atomicAdd(&hist[(w << 3) + c8], 1u << ((j & 1) << 4));
        };
        if (e < 3)       upd(ci[e + 1]);     // (0,0,+1)
        else if (vR)     upd(cR);
#pragma unroll
        for (int q = 0; q < 4; q++) {
            if (rowv[q]) {
                if (e > 0 || vL) upd(a[q][e]);
                upd(a[q][e + 1]);
                if (e < 3 || vR) upd(a[q][e + 2]);
            }
        }
    }
    __syncthreads();

    // flush: sum 8 copies per packed word, unpack halves, atomic to global partial
    unsigned int* part = ws + (size_t)(blockIdx.x & (NPART - 1)) * HSIZE;
    for (int wd = threadIdx.x; wd < HW; wd += 256) {
        const unsigned int* hh = &hist[(unsigned)wd << 3];
        uint4 u0 = *(const uint4*)hh;
        uint4 u1 = *(const uint4*)(hh + 4);
        unsigned int s = u0.x + u0.y + u0.z + u0.w + u1.x + u1.y + u1.z + u1.w;
        unsigned int lo = s & 0xFFFFu, hi = s >> 16;
        int b0 = (wd < NW) ? (wd * 2) : (NPAIR + (wd - NW) * 2);
        if (lo) atomicAdd(&part[b0], lo);
        if (hi) atomicAdd(&part[b0 + 1], hi);
    }
}

// single block, 1024 threads: coalesced sum of 32 partials, then LDS symmetrize
__global__ __launch_bounds__(1024) void final_kernel(const unsigned int* __restrict__ ws,
                                                     float* __restrict__ out) {
    __shared__ unsigned int s[NPAIR];
    __shared__ unsigned int nn[NB];
    const int k = threadIdx.x;
    unsigned int acc = 0;
#pragma unroll 8
    for (int p = 0; p < NPART; ++p) acc += ws[p * HSIZE + k];
    s[k] = acc;
    if (k < NB) {
        unsigned int a2 = 0;
#pragma unroll 8
        for (int p = 0; p < NPART; ++p) a2 += ws[p * HSIZE + NPAIR + k];
        nn[k] = a2;
    }
    __syncthreads();
    const int i = k >> 5, j = k & 31;
    unsigned int v = s[k] + s[(j << 5) | i];
    if (i == j) v += nn[i];
    out[k] = (float)v;
}

extern "C" void kernel_launch(void* const* d_in, const int* in_sizes, int n_in,
                              void* d_out, int out_size, void* d_ws, size_t ws_size,
                              hipStream_t stream) {
    const int* tgt = (const int*)d_in[0];
    float* out = (float*)d_out;
    unsigned int* ws = (unsigned int*)d_ws;

    const int zn = NPART * HSIZE;   // 33792 words
    zero_kernel<<<(zn + 255) / 256, 256, 0, stream>>>(ws, zn);
    adj_kernel<<<NBLK, 256, 0, stream>>>(tgt, ws);
    final_kernel<<<1, 1024, 0, stream>>>(ws, out);
}

// Round 7
// 23.490 us; speedup vs baseline: 1.4144x; 1.1702x over previous
//
#include <hip/hip_runtime.h>

constexpr int NB = 32;
constexpr int NPAIR = NB * NB;          // 1024 pair bins
constexpr int HSIZE = NPAIR + NB;       // 1056 bins (pairs + diag counts)
constexpr int NCPY = 4;                 // interleaved copies: addr = bin*4 + (lane&3)
constexpr int LWORDS = HSIZE * NCPY;    // 4224 words = 16.9 KB -> full occupancy
constexpr int DD = 96, HH = 96, WW = 96;
constexpr int SD = HH * WW;             // 9216
constexpr int SH = WW;                  // 96
constexpr int NVOX = 2 * DD * HH * WW;  // 1769472
constexpr int NCH = NVOX / 4;           // 442368 chunks of 4 voxels
constexpr int CW = WW / 4;              // 24 chunks per row
constexpr int NBLK = NCH / 256;         // 1728: exactly 1 chunk per thread
constexpr int NPART = 32;               // global partial histograms

__global__ void zero_kernel(unsigned int* ws, int n) {
    int t = blockIdx.x * blockDim.x + threadIdx.x;
    if (t < n) ws[t] = 0u;
}

__global__ __launch_bounds__(256) void adj_kernel(const int* __restrict__ tgt,
                                                  unsigned int* __restrict__ ws) {
    __shared__ unsigned int hist[LWORDS];
    uint4* h4 = (uint4*)hist;
    for (int k = threadIdx.x; k < LWORDS / 4; k += 256)
        h4[k] = make_uint4(0u, 0u, 0u, 0u);
    __syncthreads();

    const int c  = blockIdx.x * 256 + threadIdx.x;   // grid sized exactly
    const int cw = c % CW;
    const int r  = c / CW;
    const int h  = r % HH;
    const int d  = (r / HH) % DD;    // batch boundary handled by dp guard
    const int v0 = c * 4;
    const unsigned int cp = threadIdx.x & (NCPY - 1);   // lane's private copy

    const bool hpv = (h + 1 < HH), hmv = (h > 0), dpv = (d + 1 < DD);
    const bool vL = (cw > 0), vR = (cw < CW - 1);

    int4 Cc = *(const int4*)(tgt + v0);
    int ci[4] = {Cc.x, Cc.y, Cc.z, Cc.w};
    int cR = vR ? tgt[v0 + 4] : 0;

    // neighbor rows for the 13 lexicographically-positive offsets:
    // (0,+1,*), (+1,-1,*), (+1,0,*), (+1,+1,*); plus (0,0,+1) in-row
    bool rowv[4];
    rowv[0] = hpv; rowv[1] = dpv && hmv; rowv[2] = dpv; rowv[3] = dpv && hpv;
    const int roff[4] = {SH, SD - SH, SD, SD + SH};
    int a[4][6];
#pragma unroll
    for (int q = 0; q < 4; q++) {
        if (rowv[q]) {
            const int* p = tgt + v0 + roff[q];
            int4 m = *(const int4*)p;
            a[q][1] = m.x; a[q][2] = m.y; a[q][3] = m.z; a[q][4] = m.w;
            a[q][0] = vL ? p[-1] : 0;
            a[q][5] = vR ? p[4]  : 0;
        }
    }

#pragma unroll
    for (int e = 0; e < 4; e++) {
        // bin (i,j) at (i*32+j)*4 + cp ; diag bin i at (1024+i)*4 + cp
        const unsigned int ib4 = (((unsigned int)ci[e]) << 7) + cp;  // i*32*4 + cp
        atomicAdd(&hist[((NPAIR + ci[e]) << 2) + cp], 1u);           // center diag
        if (e < 3)       atomicAdd(&hist[ib4 + (ci[e + 1] << 2)], 1u);  // (0,0,+1)
        else if (vR)     atomicAdd(&hist[ib4 + (cR << 2)], 1u);
#pragma unroll
        for (int q = 0; q < 4; q++) {
            if (rowv[q]) {
                if (e > 0 || vL) atomicAdd(&hist[ib4 + (a[q][e] << 2)], 1u);
                atomicAdd(&hist[ib4 + (a[q][e + 1] << 2)], 1u);
                if (e < 3 || vR) atomicAdd(&hist[ib4 + (a[q][e + 2] << 2)], 1u);
            }
        }
    }
    __syncthreads();

    // flush: one contiguous uint4 per bin, sum 4 copies, atomic to global partial
    unsigned int* part = ws + (size_t)(blockIdx.x & (NPART - 1)) * HSIZE;
    for (int k = threadIdx.x; k < HSIZE; k += 256) {
        uint4 u = ((const uint4*)hist)[k];
        unsigned int s = u.x + u.y + u.z + u.w;
        if (s) atomicAdd(&part[k], s);
    }
}

// single block, 1024 threads: coalesced sum of 32 partials, then LDS symmetrize
__global__ __launch_bounds__(1024) void final_kernel(const unsigned int* __restrict__ ws,
                                                     float* __restrict__ out) {
    __shared__ unsigned int s[NPAIR];
    __shared__ unsigned int nn[NB];
    const int k = threadIdx.x;
    unsigned int acc = 0;
#pragma unroll 8
    for (int p = 0; p < NPART; ++p) acc += ws[p * HSIZE + k];
    s[k] = acc;
    if (k < NB) {
        unsigned int a2 = 0;
#pragma unroll 8
        for (int p = 0; p < NPART; ++p) a2 += ws[p * HSIZE + NPAIR + k];
        nn[k] = a2;
    }
    __syncthreads();
    const int i = k >> 5, j = k & 31;
    unsigned int v = s[k] + s[(j << 5) | i];
    if (i == j) v += nn[i];
    out[k] = (float)v;
}

extern "C" void kernel_launch(void* const* d_in, const int* in_sizes, int n_in,
                              void* d_out, int out_size, void* d_ws, size_t ws_size,
                              hipStream_t stream) {
    const int* tgt = (const int*)d_in[0];
    float* out = (float*)d_out;
    unsigned int* ws = (unsigned int*)d_ws;

    const int zn = NPART * HSIZE;   // 33792 words
    zero_kernel<<<(zn + 255) / 256, 256, 0, stream>>>(ws, zn);
    adj_kernel<<<NBLK, 256, 0, stream>>>(tgt, ws);
    final_kernel<<<1, 1024, 0, stream>>>(ws, out);
}